// Round 2
// baseline (560.897 us; speedup 1.0000x reference)
//
#include <hip/hip_runtime.h>

#define NN 16384
#define HH 32
#define GG 8
#define DD 128
#define RR 4
#define NGROUPS 4
#define NBAND 32
#define TPB 4   // tokens per block

// out layout (floats): index_q [N,4,128] | index_k [N,128] | weights [N,4]
// fold inverse: d = (n&15)*4 + (n>>4) + im*64 + (j>>3)*2
//   index_q: head = (j&7)*4 + group;  index_k: g = j&7
// j and j+8 share the same head/g and differ by d+=2 -> pair them so each
// 64-B line is fully consumed by adjacent instructions.

__global__ __launch_bounds__(256, 4) void idxer_kernel(
    const float* __restrict__ q, const float* __restrict__ k,
    const float* __restrict__ v, const float* __restrict__ proj,
    const float* __restrict__ vt, float* __restrict__ out)
{
    const int b0  = blockIdx.x * TPB;
    const int tid = threadIdx.x;
    const int im  = (tid >> 5) & 1;   // lane 0-31: im=0, lane 32-63: im=1
    const int n   = tid & 31;
    const int wav = tid >> 6;         // = group (phase 1), = token (phase 2)

    __shared__ float sv[TPB * GG * DD];   // 16 KB
    __shared__ float sw[TPB * HH];        // per-token per-head sum of squares

    // ---- proj row n -> registers (L1-resident after first touch) ----
    float pr[32];
    {
        const float4* proj4 = (const float4*)proj;
        #pragma unroll
        for (int jj = 0; jj < 8; ++jj) {
            const float4 t = proj4[n * 8 + jj];
            pr[jj * 4 + 0] = t.x; pr[jj * 4 + 1] = t.y;
            pr[jj * 4 + 2] = t.z; pr[jj * 4 + 3] = t.w;
        }
    }

    // ---- v: load to regs now (coalesced), write to LDS after compute ----
    float4 vreg[4];
    {
        const float4* v4 = (const float4*)(v + (size_t)b0 * (GG * DD));
        #pragma unroll
        for (int i = 0; i < 4; ++i) vreg[i] = v4[tid + 256 * i];
    }

    const int dbase = (n & 15) * 4 + (n >> 4) + im * 64;

    // ---- phase 1: index_q, direct global gather, wav = group ----
    {
        float2* oq2 = (float2*)out;
        #pragma unroll
        for (int t = 0; t < TPB; ++t) {
            const float* qb = q + (size_t)(b0 + t) * (HH * DD);
            float a0 = 0.f, a1 = 0.f;
            #pragma unroll
            for (int jj = 0; jj < 8; ++jj) {
                const int head = jj * 4 + wav;
                const float q0 = qb[head * DD + dbase];       // j = jj
                const float q1 = qb[head * DD + dbase + 2];   // j = jj+8
                a0 += q0 * pr[2 * jj];
                a1 += q0 * pr[2 * jj + 1];
                a0 += q1 * pr[2 * (jj + 8)];
                a1 += q1 * pr[2 * (jj + 8) + 1];
            }
            oq2[(size_t)(b0 + t) * 256 + wav * 64 + im * 32 + n] =
                make_float2(a0, a1);
        }
    }

    // ---- phase 2: index_k, wav = token ----
    {
        const float* kb = k + (size_t)(b0 + wav) * (GG * DD);
        float a0 = 0.f, a1 = 0.f;
        #pragma unroll
        for (int jj = 0; jj < 8; ++jj) {
            const float k0 = kb[jj * DD + dbase];
            const float k1 = kb[jj * DD + dbase + 2];
            a0 += k0 * pr[2 * jj];
            a1 += k0 * pr[2 * jj + 1];
            a0 += k1 * pr[2 * (jj + 8)];
            a1 += k1 * pr[2 * (jj + 8) + 1];
        }
        float2* ok2 = (float2*)(out + (size_t)NN * 512);
        ok2[(size_t)(b0 + wav) * 64 + im * 32 + n] = make_float2(a0, a1);
    }

    // ---- commit v to LDS, then barrier ----
    {
        float4* s4 = (float4*)sv;
        #pragma unroll
        for (int i = 0; i < 4; ++i) s4[tid + 256 * i] = vreg[i];
    }
    __syncthreads();

    // ---- phase 3: weights. thread = h*8 + s, loop tokens ----
    {
        const int h = tid >> 3;
        const int s = tid & 7;
        const int g = h >> 2;
        const float4* vt4 = (const float4*)vt;   // [H][D] float4 over R
        float acc[TPB][4];
        #pragma unroll
        for (int t = 0; t < TPB; ++t)
            acc[t][0] = acc[t][1] = acc[t][2] = acc[t][3] = 0.f;
        #pragma unroll
        for (int i = 0; i < 16; ++i) {
            const int d = i * 8 + s;
            const float4 w4 = vt4[h * DD + d];
            #pragma unroll
            for (int t = 0; t < TPB; ++t) {
                const float vv = sv[t * (GG * DD) + g * DD + d];
                acc[t][0] += vv * w4.x; acc[t][1] += vv * w4.y;
                acc[t][2] += vv * w4.z; acc[t][3] += vv * w4.w;
            }
        }
        #pragma unroll
        for (int t = 0; t < TPB; ++t) {
            #pragma unroll
            for (int off = 4; off >= 1; off >>= 1) {
                acc[t][0] += __shfl_down(acc[t][0], off, 8);
                acc[t][1] += __shfl_down(acc[t][1], off, 8);
                acc[t][2] += __shfl_down(acc[t][2], off, 8);
                acc[t][3] += __shfl_down(acc[t][3], off, 8);
            }
            if (s == 0)
                sw[t * HH + h] = acc[t][0] * acc[t][0] + acc[t][1] * acc[t][1]
                               + acc[t][2] * acc[t][2] + acc[t][3] * acc[t][3];
        }
    }
    __syncthreads();

    if (tid < TPB * NGROUPS) {
        const int t = tid >> 2;
        const int grp = tid & 3;
        float acc = 0.f;
        #pragma unroll
        for (int g8 = 0; g8 < 8; ++g8) acc += sw[t * HH + g8 * 4 + grp];
        out[(size_t)NN * 512 + (size_t)NN * 128 + (size_t)(b0 + t) * 4 + grp] =
            sqrtf(acc);
    }
}

extern "C" void kernel_launch(void* const* d_in, const int* in_sizes, int n_in,
                              void* d_out, int out_size, void* d_ws, size_t ws_size,
                              hipStream_t stream) {
    const float* q    = (const float*)d_in[0];
    const float* k    = (const float*)d_in[1];
    const float* v    = (const float*)d_in[2];
    const float* proj = (const float*)d_in[3];
    const float* vt   = (const float*)d_in[4];
    float* out = (float*)d_out;
    idxer_kernel<<<NN / TPB, 256, 0, stream>>>(q, k, v, proj, vt, out);
}